// Round 12
// baseline (3493.935 us; speedup 1.0000x reference)
//
#include <hip/hip_runtime.h>

// RLIF forward, persistent kernel, stamp-in-word sync.
// Round 12 = Round 10 (PASS @1576us) with ONE structural change: wave-3-only poll.
//  - Lane l of wave 3 owns group-row l>>1 and 32 stamped u32 words, read as 8
//    independent global_load_dwordx4 sc0 sc1 -> ONE waitcnt -> ~1 fabric RTT per
//    round (R6 serialized 8 RTTs). Retry only pending quads, s_sleep(4) backoff.
//  - Poll traffic per round: 64 lanes/wg instead of 256 threads x N words:
//    131K vs 524K chip-wide transactions (R8/R10's hot storm cost +80MB FETCH).
//  - Publish unchanged: atomicExch stamped words (proven R5-R10), publish-first.
//  - Triple buffer, ys layout/contents, Wr 3-split LDS, single MFMA chain,
//    epilogue arithmetic: byte-identical to the R10 PASS.

#define T_STEPS 256
#define BATCH   128
#define NNEUR   1024
#define DECAY_F 0.2f
#define THRESH  0.3f

typedef __attribute__((ext_vector_type(8))) short short8;
typedef __attribute__((ext_vector_type(4))) float f32x4;
typedef __attribute__((ext_vector_type(4))) unsigned uint4v;

union FU { short8 s; unsigned u[4]; };

__device__ __forceinline__ unsigned short f2bf_rn(float x) {
    unsigned u = __float_as_uint(x);
    return (unsigned short)((u + 0x7FFFu + ((u >> 16) & 1u)) >> 16);
}

__global__ void rlif_init(unsigned* __restrict__ ybits) {
    int i = blockIdx.x * 256 + threadIdx.x;
    if (i < 3 * BATCH * 64) ybits[i] = 0xFFFF0000u;   // stamp 0xFFFF: never matches t
}

__global__ __launch_bounds__(256, 1)
void rlif_persist(const float* __restrict__ tx,   // [T][B][N]
                  const float* __restrict__ Wr,   // [N][N]
                  const float* __restrict__ br,   // [N]
                  float* __restrict__ out,        // [T][B][N]
                  unsigned* __restrict__ ybits)   // [3][128][64] stamped words
{
    extern __shared__ char smem[];
    unsigned short* wlds = (unsigned short*)smem;        // 3 * [16][1024] bf16, swizzled
    float* red = (float*)(smem + 3 * 16 * 1024 * 2);     // [2][16][16] f32 k-reduce
    unsigned short* ys = (unsigned short*)(smem + 3 * 16 * 1024 * 2 + 2 * 16 * 16 * 4); // [32][66]

    const int tid = threadIdx.x;
    const int bb  = blockIdx.x >> 6;   // 0..3  batch-block (32 batches)
    const int ib  = blockIdx.x & 63;   // 0..63 neuron-block (16 neurons)
    const int i0  = ib * 16;
    const int b0  = bb * 32;
    const int w   = tid >> 6;          // wave 0..3
    const int l   = tid & 63;
    const int c   = l & 15;
    const int kg  = l >> 4;
    const int r   = w & 1;             // row-tile
    const int h   = w >> 1;            // k-half

    // ---- one-time: stage Wr rows [i0, i0+16) as exact 3-way bf16 split, swizzled ----
    for (int e = tid * 4; e < 16 * NNEUR; e += 256 * 4) {
        int row = e >> 10;
        int k   = e & 1023;
        float4 wv = *(const float4*)(Wr + (size_t)(i0 + row) * NNEUR + k);
        int ksw = k ^ ((row & 7) << 3);
        float wa[4] = {wv.x, wv.y, wv.z, wv.w};
        #pragma unroll
        for (int j = 0; j < 4; ++j) {
            float fw = wa[j];
            unsigned short hb = f2bf_rn(fw);
            float hf = __uint_as_float((unsigned)hb << 16);
            float rm = fw - hf;
            unsigned short mb = f2bf_rn(rm);
            float mf = __uint_as_float((unsigned)mb << 16);
            float rl = rm - mf;
            unsigned short lb = f2bf_rn(rl);
            wlds[0 * 16384 + row * 1024 + ksw + j] = hb;
            wlds[1 * 16384 + row * 1024 + ksw + j] = mb;
            wlds[2 * 16384 + row * 1024 + ksw + j] = lb;
        }
    }
    __syncthreads();

    const float brv = br[i0 + c];
    float vreg[4] = {0.f, 0.f, 0.f, 0.f};
    const size_t BN = (size_t)BATCH * NNEUR;

    for (int t = 0; t < T_STEPS; ++t) {
        float txv[4];
        if (w < 2) {
            #pragma unroll
            for (int j = 0; j < 4; ++j)
                txv[j] = tx[(size_t)t * BN + (size_t)(b0 + w * 16 + kg * 4 + j) * NNEUR + i0 + c];
        }

        // ---- stage spikes of step t-1 into LDS: wave 3 wide-poll, 1 RTT/round ----
        if (t > 0 && w == 3) {
            const unsigned* qb = ybits + (size_t)((t - 1) % 3) * (BATCH * 64);
            const unsigned want = (unsigned)(t - 1);
            const int prow = l >> 1;          // row within group 0..31
            const int pc0  = (l & 1) * 32;    // starting u32 col: 0 or 32
            const unsigned* base = qb + (size_t)(b0 + prow) * 64 + pc0;
            unsigned pend = 0xFFu;
            uint4v q[8];
            for (;;) {
                #pragma unroll
                for (int i = 0; i < 8; ++i) {
                    if (pend & (1u << i)) {
                        asm volatile("global_load_dwordx4 %0, %1, off sc0 sc1"
                                     : "=&v"(q[i]) : "v"(base + i * 4) : "memory");
                    }
                }
                asm volatile("s_waitcnt vmcnt(0)" ::: "memory");
                #pragma unroll
                for (int i = 0; i < 8; ++i) {
                    if (pend & (1u << i)) {
                        unsigned w0 = q[i].x, w1 = q[i].y, w2 = q[i].z, w3 = q[i].w;
                        if (((w0 >> 16) == want) & ((w1 >> 16) == want) &
                            ((w2 >> 16) == want) & ((w3 >> 16) == want)) {
                            int c4 = pc0 + i * 4;
                            *(unsigned*)&ys[prow * 66 + c4]     = (w0 & 0xFFFFu) | (w1 << 16);
                            *(unsigned*)&ys[prow * 66 + c4 + 2] = (w2 & 0xFFFFu) | (w3 << 16);
                            pend &= ~(1u << i);
                        }
                    }
                }
                if (!pend) break;
                __builtin_amdgcn_s_sleep(4);
            }
        }
        __syncthreads();

        f32x4 acc = {0.f, 0.f, 0.f, 0.f};
        if (t > 0) {
            // A-frags: bf16 1.0 / 0.0 bit patterns (identical to rounds 2/5/6/8/10)
            short8 afr[16];
            #pragma unroll
            for (int ks = 0; ks < 16; ++ks) {
                unsigned wv = *(const unsigned*)(ys + (r * 16 + c) * 66 + 2 * (h * 16 + ks));
                unsigned byt = (wv >> (kg * 8)) & 0xFFu;
                FU f;
                #pragma unroll
                for (int q2 = 0; q2 < 4; ++q2) {
                    f.u[q2] = (((byt >> (2 * q2)) & 1u) ? 0x00003F80u : 0u)
                            | (((byt >> (2 * q2 + 1)) & 1u) ? 0x3F800000u : 0u);
                }
                afr[ks] = f.s;
            }
            // single accumulator chain, mat-outer / ks-inner — proven exact order
            #pragma unroll
            for (int mat = 0; mat < 3; ++mat) {
                #pragma unroll
                for (int ks = 0; ks < 16; ++ks) {
                    int kel = h * 512 + ks * 32 + kg * 8;
                    int sw  = kel ^ ((c & 7) << 3);
                    short8 bfr = *(const short8*)(wlds + mat * 16384 + c * 1024 + sw);
                    acc = __builtin_amdgcn_mfma_f32_16x16x32_bf16(afr[ks], bfr, acc, 0, 0, 0);
                }
            }
        }

        if (w >= 2) {
            #pragma unroll
            for (int j = 0; j < 4; ++j)
                red[r * 256 + (kg * 4 + j) * 16 + c] = acc[j];
        }
        __syncthreads();

        if (w < 2) {
            float* op = out + (size_t)t * BN;
            unsigned* pbuf = ybits + (size_t)(t % 3) * (BATCH * 64);
            int   sp4[4];
            unsigned long long mball[4];
            #pragma unroll
            for (int j = 0; j < 4; ++j) {
                float z  = acc[j] + red[w * 256 + (kg * 4 + j) * 16 + c];
                float x  = (txv[j] + z) + brv;
                float vv = DECAY_F * vreg[j] + x;
                int   sp = vv > THRESH;
                vreg[j]  = sp ? 0.f : vv;
                sp4[j]   = sp;
                mball[j] = __ballot(sp != 0);
            }
            // publish FIRST (critical path: peers poll these words)
            #pragma unroll
            for (int j = 0; j < 4; ++j) {
                if (c == j) {
                    unsigned u16v = (unsigned)((mball[j] >> (kg * 16)) & 0xFFFFu);
                    atomicExch(&pbuf[(b0 + w * 16 + kg * 4 + j) * 64 + ib],
                               ((unsigned)t << 16) | u16v);
                }
            }
            // then the out-slab stores (no intra-kernel consumer)
            #pragma unroll
            for (int j = 0; j < 4; ++j)
                op[(size_t)(b0 + w * 16 + kg * 4 + j) * NNEUR + i0 + c] = sp4[j] ? 1.f : 0.f;
        }
        // no end-of-step barrier: stamp polling is the synchronization
    }
}

extern "C" void kernel_launch(void* const* d_in, const int* in_sizes, int n_in,
                              void* d_out, int out_size, void* d_ws, size_t ws_size,
                              hipStream_t stream)
{
    const float* tx = (const float*)d_in[0];
    const float* Wr = (const float*)d_in[1];
    const float* br = (const float*)d_in[2];
    float* out = (float*)d_out;
    unsigned* ybits = (unsigned*)d_ws;   // [3][128][64] u32 = 96 KB

    const int lds_bytes = 3 * 16 * 1024 * 2 + 2 * 16 * 16 * 4 + 32 * 66 * 2;  // 103552
    hipFuncSetAttribute(reinterpret_cast<const void*>(rlif_persist),
                        hipFuncAttributeMaxDynamicSharedMemorySize, lds_bytes);

    rlif_init<<<dim3(96), dim3(256), 0, stream>>>(ybits);
    rlif_persist<<<dim3(256), dim3(256), lds_bytes, stream>>>(tx, Wr, br, out, ybits);
}

// Round 13
// 2028.822 us; speedup vs baseline: 1.7221x; 1.7221x over previous
//
#include <hip/hip_runtime.h>

// RLIF forward, persistent kernel, stamp-in-word sync.
// Round 13 = R6/R10 skeleton + wave-quadrant polling.
//  Matrix so far: R6 serial-guarded+sleep=1354us/190MB; R8/R10 batched=1576/272;
//  R12 single-wave=3494/575. dur tracks FETCH tracks per-word poll frequency.
//  Changes:
//   - each wave polls/stages ONLY its own MFMA quadrant (rows r*16..+15,
//     qwords h*16..+15): producer set per wave 64->32 wgs, staging barrier
//     (sync1) deleted -> one barrier/step (red double-buffered).
//   - poll = 4 parallel stamped-qword agent loads per lane + s_sleep(2)/round
//     (explicit ~128cy+RTT per-word sample period).
//  Publish (atomicExch, triple buffer, publish-first) and the full datapath
//  (Wr 3-split LDS, ys contents, single MFMA chain, epilogue order) frozen.

#define T_STEPS 256
#define BATCH   128
#define NNEUR   1024
#define DECAY_F 0.2f
#define THRESH  0.3f

typedef __attribute__((ext_vector_type(8))) short short8;
typedef __attribute__((ext_vector_type(4))) float f32x4;

union FU { short8 s; unsigned u[4]; };

__device__ __forceinline__ unsigned short f2bf_rn(float x) {
    unsigned u = __float_as_uint(x);
    return (unsigned short)((u + 0x7FFFu + ((u >> 16) & 1u)) >> 16);
}

__global__ void rlif_init(unsigned* __restrict__ ybits) {
    int i = blockIdx.x * 256 + threadIdx.x;
    if (i < 3 * BATCH * 64) ybits[i] = 0xFFFF0000u;   // stamp 0xFFFF: never matches t
}

__global__ __launch_bounds__(256, 1)
void rlif_persist(const float* __restrict__ tx,   // [T][B][N]
                  const float* __restrict__ Wr,   // [N][N]
                  const float* __restrict__ br,   // [N]
                  float* __restrict__ out,        // [T][B][N]
                  unsigned* __restrict__ ybits)   // [3][128][64] stamped words
{
    extern __shared__ char smem[];
    unsigned short* wlds = (unsigned short*)smem;        // 3 * [16][1024] bf16, swizzled
    float* red = (float*)(smem + 3 * 16 * 1024 * 2);     // [2 buf][2 r][16][16] f32
    unsigned short* ys = (unsigned short*)(smem + 3 * 16 * 1024 * 2 + 4 * 16 * 16 * 4); // [32][66]

    const int tid = threadIdx.x;
    const int bb  = blockIdx.x >> 6;   // 0..3  batch-block (32 batches)
    const int ib  = blockIdx.x & 63;   // 0..63 neuron-block (16 neurons)
    const int i0  = ib * 16;
    const int b0  = bb * 32;
    const int w   = tid >> 6;          // wave 0..3
    const int l   = tid & 63;
    const int c   = l & 15;
    const int kg  = l >> 4;
    const int r   = w & 1;             // row-tile
    const int h   = w >> 1;            // k-half

    // ---- one-time: stage Wr rows [i0, i0+16) as exact 3-way bf16 split, swizzled ----
    for (int e = tid * 4; e < 16 * NNEUR; e += 256 * 4) {
        int row = e >> 10;
        int k   = e & 1023;
        float4 wv = *(const float4*)(Wr + (size_t)(i0 + row) * NNEUR + k);
        int ksw = k ^ ((row & 7) << 3);
        float wa[4] = {wv.x, wv.y, wv.z, wv.w};
        #pragma unroll
        for (int j = 0; j < 4; ++j) {
            float fw = wa[j];
            unsigned short hb = f2bf_rn(fw);
            float hf = __uint_as_float((unsigned)hb << 16);
            float rm = fw - hf;
            unsigned short mb = f2bf_rn(rm);
            float mf = __uint_as_float((unsigned)mb << 16);
            float rl = rm - mf;
            unsigned short lb = f2bf_rn(rl);
            wlds[0 * 16384 + row * 1024 + ksw + j] = hb;
            wlds[1 * 16384 + row * 1024 + ksw + j] = mb;
            wlds[2 * 16384 + row * 1024 + ksw + j] = lb;
        }
    }
    __syncthreads();

    const float brv = br[i0 + c];
    float vreg[4] = {0.f, 0.f, 0.f, 0.f};
    const size_t BN = (size_t)BATCH * NNEUR;

    // quadrant poll geometry: lane owns row r*16+(l&15), qwords h*16+(l>>4)*4 ..+3
    const int rowl = r * 16 + c;            // row within group block (0..31)
    const int qw0  = h * 16 + kg * 4;       // first owned qword index (0..31)

    for (int t = 0; t < T_STEPS; ++t) {
        float txv[4];
        if (w < 2) {
            #pragma unroll
            for (int j = 0; j < 4; ++j)
                txv[j] = tx[(size_t)t * BN + (size_t)(b0 + w * 16 + kg * 4 + j) * NNEUR + i0 + c];
        }

        // ---- stage own quadrant of step t-1 spikes: stamped-qword poll + backoff ----
        if (t > 0) {
            const unsigned long long* qb =
                (const unsigned long long*)(ybits + (size_t)((t - 1) % 3) * (BATCH * 64))
                + (size_t)(b0 + rowl) * 32 + qw0;
            const unsigned want = (unsigned)(t - 1);
            unsigned pend = 0xFu;
            for (;;) {
                unsigned long long qv[4];
                #pragma unroll
                for (int k = 0; k < 4; ++k)
                    if (pend & (1u << k))
                        qv[k] = __hip_atomic_load(qb + k, __ATOMIC_RELAXED,
                                                  __HIP_MEMORY_SCOPE_AGENT);
                #pragma unroll
                for (int k = 0; k < 4; ++k) {
                    if (pend & (1u << k)) {
                        unsigned lo = (unsigned)qv[k];
                        unsigned hi = (unsigned)(qv[k] >> 32);
                        if (((lo >> 16) == want) & ((hi >> 16) == want)) {
                            *(unsigned*)&ys[rowl * 66 + 2 * (qw0 + k)] =
                                (lo & 0xFFFFu) | (hi << 16);
                            pend &= ~(1u << k);
                        }
                    }
                }
                if (!pend) break;
                __builtin_amdgcn_s_sleep(2);
            }
        }
        // no barrier: each wave staged exactly the ys quadrant it consumes

        f32x4 acc = {0.f, 0.f, 0.f, 0.f};
        if (t > 0) {
            // A-frags: bf16 1.0 / 0.0 bit patterns (identical to rounds 2/5/6/8/10)
            short8 afr[16];
            #pragma unroll
            for (int ks = 0; ks < 16; ++ks) {
                unsigned wv = *(const unsigned*)(ys + (r * 16 + c) * 66 + 2 * (h * 16 + ks));
                unsigned byt = (wv >> (kg * 8)) & 0xFFu;
                FU f;
                #pragma unroll
                for (int q2 = 0; q2 < 4; ++q2) {
                    f.u[q2] = (((byt >> (2 * q2)) & 1u) ? 0x00003F80u : 0u)
                            | (((byt >> (2 * q2 + 1)) & 1u) ? 0x3F800000u : 0u);
                }
                afr[ks] = f.s;
            }
            // single accumulator chain, mat-outer / ks-inner — proven exact order
            #pragma unroll
            for (int mat = 0; mat < 3; ++mat) {
                #pragma unroll
                for (int ks = 0; ks < 16; ++ks) {
                    int kel = h * 512 + ks * 32 + kg * 8;
                    int sw  = kel ^ ((c & 7) << 3);
                    short8 bfr = *(const short8*)(wlds + mat * 16384 + c * 1024 + sw);
                    acc = __builtin_amdgcn_mfma_f32_16x16x32_bf16(afr[ks], bfr, acc, 0, 0, 0);
                }
            }
        }

        float* redb = red + (t & 1) * 512;
        if (w >= 2) {
            #pragma unroll
            for (int j = 0; j < 4; ++j)
                redb[r * 256 + (kg * 4 + j) * 16 + c] = acc[j];
        }
        __syncthreads();   // the single per-step barrier (red handoff)

        if (w < 2) {
            float* op = out + (size_t)t * BN;
            unsigned* pbuf = ybits + (size_t)(t % 3) * (BATCH * 64);
            int   sp4[4];
            unsigned long long mball[4];
            #pragma unroll
            for (int j = 0; j < 4; ++j) {
                float z  = acc[j] + redb[w * 256 + (kg * 4 + j) * 16 + c];
                float x  = (txv[j] + z) + brv;
                float vv = DECAY_F * vreg[j] + x;
                int   sp = vv > THRESH;
                vreg[j]  = sp ? 0.f : vv;
                sp4[j]   = sp;
                mball[j] = __ballot(sp != 0);
            }
            // publish FIRST (critical path: peers poll these words)
            #pragma unroll
            for (int j = 0; j < 4; ++j) {
                if (c == j) {
                    unsigned u16v = (unsigned)((mball[j] >> (kg * 16)) & 0xFFFFu);
                    atomicExch(&pbuf[(b0 + w * 16 + kg * 4 + j) * 64 + ib],
                               ((unsigned)t << 16) | u16v);
                }
            }
            // then the out-slab stores (no intra-kernel consumer)
            #pragma unroll
            for (int j = 0; j < 4; ++j)
                op[(size_t)(b0 + w * 16 + kg * 4 + j) * NNEUR + i0 + c] = sp4[j] ? 1.f : 0.f;
        }
        // no end-of-step barrier: stamp polling is the synchronization
    }
}

extern "C" void kernel_launch(void* const* d_in, const int* in_sizes, int n_in,
                              void* d_out, int out_size, void* d_ws, size_t ws_size,
                              hipStream_t stream)
{
    const float* tx = (const float*)d_in[0];
    const float* Wr = (const float*)d_in[1];
    const float* br = (const float*)d_in[2];
    float* out = (float*)d_out;
    unsigned* ybits = (unsigned*)d_ws;   // [3][128][64] u32 = 96 KB

    const int lds_bytes = 3 * 16 * 1024 * 2 + 4 * 16 * 16 * 4 + 32 * 66 * 2;  // 106624
    hipFuncSetAttribute(reinterpret_cast<const void*>(rlif_persist),
                        hipFuncAttributeMaxDynamicSharedMemorySize, lds_bytes);

    rlif_init<<<dim3(96), dim3(256), 0, stream>>>(ybits);
    rlif_persist<<<dim3(256), dim3(256), lds_bytes, stream>>>(tx, Wr, br, out, ybits);
}

// Round 14
// 1229.573 us; speedup vs baseline: 2.8416x; 1.6500x over previous
//
#include <hip/hip_runtime.h>

// RLIF forward, persistent kernel, stamp-in-word sync (R6 skeleton, frozen).
// Round 14: Wr 3-way bf16 split moves LDS -> REGISTERS (fr0/fr1/fr2[16] short8
// = 192 VGPR; launch_bounds(256,1) + 1 wave/SIMD gives ~512 VGPR budget, m08).
//  - deletes 96KB wlds, the staging loop, 48 ds_read_b128/step and the 5.2e7
//    bank conflicts; MFMA chain is pure-register; VGPR>256 guarantees 1 wg/CU.
//  - fragment VALUES, chain order (mat0,mat1,mat2 x ks 0..15), A-frags, and
//    epilogue arithmetic are bit-identical to the R6 PASS.
//  - poll loop (serialized guarded loads + s_sleep(1)), publish (atomicExch
//    stamp-in-word, triple buffer), init: byte-identical to R6 (best measured).

#define T_STEPS 256
#define BATCH   128
#define NNEUR   1024
#define DECAY_F 0.2f
#define THRESH  0.3f

typedef __attribute__((ext_vector_type(8))) short short8;
typedef __attribute__((ext_vector_type(4))) float f32x4;

union FU { short8 s; unsigned u[4]; };
union S8 { short8 s; unsigned short us[8]; };

__device__ __forceinline__ unsigned short f2bf_rn(float x) {
    unsigned u = __float_as_uint(x);
    return (unsigned short)((u + 0x7FFFu + ((u >> 16) & 1u)) >> 16);
}

__global__ void rlif_init(unsigned* __restrict__ ybits) {
    int i = blockIdx.x * 256 + threadIdx.x;
    if (i < 3 * BATCH * 64) ybits[i] = 0xFFFF0000u;   // stamp 0xFFFF: never matches t
}

__global__ __launch_bounds__(256, 1)
void rlif_persist(const float* __restrict__ tx,   // [T][B][N]
                  const float* __restrict__ Wr,   // [N][N]
                  const float* __restrict__ br,   // [N]
                  float* __restrict__ out,        // [T][B][N]
                  unsigned* __restrict__ ybits)   // [3][128][64] stamped words
{
    extern __shared__ char smem[];
    float* red = (float*)smem;                                // [2][16][16] f32
    unsigned short* ys = (unsigned short*)(smem + 2*16*16*4); // [32][66]

    const int tid = threadIdx.x;
    const int bb  = blockIdx.x >> 6;   // 0..3  batch-block (32 batches)
    const int ib  = blockIdx.x & 63;   // 0..63 neuron-block (16 neurons)
    const int i0  = ib * 16;
    const int b0  = bb * 32;
    const int w   = tid >> 6;          // wave 0..3
    const int l   = tid & 63;
    const int c   = l & 15;
    const int kg  = l >> 4;
    const int r   = w & 1;             // row-tile
    const int h   = w >> 1;            // k-half

    // ---- one-time: this lane's Wr B-fragments, exact 3-way bf16 split, in regs ----
    // lane (c,kg), wave-half h holds Wr[i0+c][h*512 + ks*32 + kg*8 .. +8] for ks 0..15
    short8 fr0[16], fr1[16], fr2[16];
    {
        const float* wrow = Wr + (size_t)(i0 + c) * NNEUR + h * 512 + kg * 8;
        #pragma unroll
        for (int ks = 0; ks < 16; ++ks) {
            float4 a = *(const float4*)(wrow + ks * 32);
            float4 b = *(const float4*)(wrow + ks * 32 + 4);
            float fv[8] = {a.x, a.y, a.z, a.w, b.x, b.y, b.z, b.w};
            S8 vh, vm, vl;
            #pragma unroll
            for (int e = 0; e < 8; ++e) {
                float fw = fv[e];
                unsigned short hb = f2bf_rn(fw);
                float hf = __uint_as_float((unsigned)hb << 16);
                float rm = fw - hf;                     // exact (Sterbenz)
                unsigned short mb = f2bf_rn(rm);
                float mf = __uint_as_float((unsigned)mb << 16);
                float rl = rm - mf;                     // exact; fits bf16
                vh.us[e] = hb; vm.us[e] = mb; vl.us[e] = f2bf_rn(rl);
            }
            fr0[ks] = vh.s; fr1[ks] = vm.s; fr2[ks] = vl.s;
        }
    }
    __syncthreads();

    const float brv = br[i0 + c];
    float vreg[4] = {0.f, 0.f, 0.f, 0.f};
    const size_t BN = (size_t)BATCH * NNEUR;

    for (int t = 0; t < T_STEPS; ++t) {
        float txv[4];
        if (w < 2) {
            #pragma unroll
            for (int j = 0; j < 4; ++j)
                txv[j] = tx[(size_t)t * BN + (size_t)(b0 + w * 16 + kg * 4 + j) * NNEUR + i0 + c];
        }

        // ---- stage spikes of step t-1 into LDS (R6 poll, byte-identical) ----
        if (t > 0) {
            unsigned* buf = ybits + (size_t)((t - 1) % 3) * (BATCH * 64);
            const unsigned want = (unsigned)(t - 1);
            unsigned pend = 0xFFu;    // 8 words per thread: wi = k*256 + tid
            for (;;) {
                #pragma unroll
                for (int k = 0; k < 8; ++k) {
                    if (pend & (1u << k)) {
                        int wi  = (k << 8) | tid;       // 0..2047
                        int row = wi >> 6;              // 0..31 (batch within block)
                        int col = wi & 63;              // writer wg column
                        unsigned v = __hip_atomic_load(&buf[(b0 + row) * 64 + col],
                                                       __ATOMIC_RELAXED, __HIP_MEMORY_SCOPE_AGENT);
                        if ((v >> 16) == want) {
                            ys[row * 66 + col] = (unsigned short)(v & 0xFFFFu);
                            pend &= ~(1u << k);
                        }
                    }
                }
                if (!pend) break;
                __builtin_amdgcn_s_sleep(1);
            }
        }
        __syncthreads();

        f32x4 acc = {0.f, 0.f, 0.f, 0.f};
        if (t > 0) {
            // A-frags: bf16 1.0 / 0.0 bit patterns (identical to rounds 2/5/6)
            short8 afr[16];
            #pragma unroll
            for (int ks = 0; ks < 16; ++ks) {
                unsigned wv = *(const unsigned*)(ys + (r * 16 + c) * 66 + 2 * (h * 16 + ks));
                unsigned byt = (wv >> (kg * 8)) & 0xFFu;
                FU f;
                #pragma unroll
                for (int q = 0; q < 4; ++q) {
                    f.u[q] = (((byt >> (2 * q)) & 1u) ? 0x00003F80u : 0u)
                           | (((byt >> (2 * q + 1)) & 1u) ? 0x3F800000u : 0u);
                }
                afr[ks] = f.s;
            }
            // single accumulator chain, mat-outer / ks-inner — proven exact order
            #pragma unroll
            for (int ks = 0; ks < 16; ++ks)
                acc = __builtin_amdgcn_mfma_f32_16x16x32_bf16(afr[ks], fr0[ks], acc, 0, 0, 0);
            #pragma unroll
            for (int ks = 0; ks < 16; ++ks)
                acc = __builtin_amdgcn_mfma_f32_16x16x32_bf16(afr[ks], fr1[ks], acc, 0, 0, 0);
            #pragma unroll
            for (int ks = 0; ks < 16; ++ks)
                acc = __builtin_amdgcn_mfma_f32_16x16x32_bf16(afr[ks], fr2[ks], acc, 0, 0, 0);
        }

        if (w >= 2) {
            #pragma unroll
            for (int j = 0; j < 4; ++j)
                red[r * 256 + (kg * 4 + j) * 16 + c] = acc[j];
        }
        __syncthreads();

        if (w < 2) {
            float* op = out + (size_t)t * BN;
            unsigned* pbuf = ybits + (size_t)(t % 3) * (BATCH * 64);
            #pragma unroll
            for (int j = 0; j < 4; ++j) {
                float z  = acc[j] + red[w * 256 + (kg * 4 + j) * 16 + c];
                float x  = (txv[j] + z) + brv;
                float vv = DECAY_F * vreg[j] + x;
                int   sp = vv > THRESH;
                vreg[j]  = sp ? 0.f : vv;
                op[(size_t)(b0 + w * 16 + kg * 4 + j) * NNEUR + i0 + c] = sp ? 1.f : 0.f;
                unsigned long long m = __ballot(sp != 0);
                if (c == j) {
                    unsigned u16v = (unsigned)((m >> (kg * 16)) & 0xFFFFu);
                    atomicExch(&pbuf[(b0 + w * 16 + kg * 4 + j) * 64 + ib],
                               ((unsigned)t << 16) | u16v);
                }
            }
        }
        // no end-of-step barrier: stamp polling is the synchronization
    }
}

extern "C" void kernel_launch(void* const* d_in, const int* in_sizes, int n_in,
                              void* d_out, int out_size, void* d_ws, size_t ws_size,
                              hipStream_t stream)
{
    const float* tx = (const float*)d_in[0];
    const float* Wr = (const float*)d_in[1];
    const float* br = (const float*)d_in[2];
    float* out = (float*)d_out;
    unsigned* ybits = (unsigned*)d_ws;   // [3][128][64] u32 = 96 KB

    const int lds_bytes = 2 * 16 * 16 * 4 + 32 * 66 * 2;   // 6272
    hipFuncSetAttribute(reinterpret_cast<const void*>(rlif_persist),
                        hipFuncAttributeMaxDynamicSharedMemorySize, lds_bytes);

    rlif_init<<<dim3(96), dim3(256), 0, stream>>>(ybits);
    rlif_persist<<<dim3(256), dim3(256), lds_bytes, stream>>>(tx, Wr, br, out, ybits);
}